// Round 3
// baseline (290.697 us; speedup 1.0000x reference)
//
#include <hip/hip_runtime.h>
#include <hip/hip_bf16.h>

#define N_ROWS 262144
#define DDIM   256
#define PROTO  512
#define BM     64
#define TILES  4
#define GBLK   1024
#define A_STRIDE 264   // ushorts per row (528B = 33*16B): read/write bank-minimal

typedef __bf16 bf16x8 __attribute__((ext_vector_type(8)));
typedef float  f32x4  __attribute__((ext_vector_type(4)));

// ---------------- prep: prototypes fp32 -> bf16 in MFMA-fragment order, p2 ----------------
// idx = (p>>4)*4096 + (k>>5)*512 + ((((k>>3)&3)*16) + (p&15))*8 + (k&7)
// A wave's bg fragment load is then a fully coalesced 16B/lane read.
__global__ void prep_proto(const float* __restrict__ Pm,
                           unsigned short* __restrict__ PBf,
                           float* __restrict__ P2) {
  int p = blockIdx.x;     // 512
  int k = threadIdx.x;    // 256
  float v = Pm[p * DDIM + k];
  int idx = (p >> 4) * 4096 + (k >> 5) * 512 + ((((k >> 3) & 3) * 16) + (p & 15)) * 8 + (k & 7);
  ((__bf16*)PBf)[idx] = (__bf16)v;
  float sq = v * v;
  #pragma unroll
  for (int m = 1; m < 64; m <<= 1) sq += __shfl_xor(sq, m);
  __shared__ float ws4[4];
  if ((k & 63) == 0) ws4[k >> 6] = sq;
  __syncthreads();
  if (k == 0) P2[p] = (ws4[0] + ws4[1]) + (ws4[2] + ws4[3]);
}

// ---------------- main: fused GEMM + row/col min ----------------
// grid 1024 x block 1024 (16 waves, 4/SIMD, 1 block/CU). Block b: rows [b*256, b*256+256).
// Wave w owns proto cols [w*32, w*32+32). B regs hold a K=128 half (32 VGPR), reloaded
// per half per tile from L2-hot PBf. A-tile prefetched into regs across the barrier (T14).
__global__ __attribute__((amdgpu_flat_work_group_size(1024, 1024), amdgpu_waves_per_eu(4, 4)))
void proto_main(const float* __restrict__ Z, const unsigned short* __restrict__ PBf,
                const float* __restrict__ P2, float* __restrict__ colpart,
                float* __restrict__ rowpart) {
  __shared__ __align__(16) unsigned short A_lds[BM * A_STRIDE];  // 33792 B
  __shared__ float z2s[BM];
  __shared__ float rowred[BM * 16];                              // 4096 B

  const int t   = threadIdx.x;
  const int w   = t >> 6;   // wave 0..15
  const int l   = t & 63;
  const int l15 = l & 15;
  const int lg  = l >> 4;   // 0..3

  const int srow = t >> 4;  // staging row 0..63 (16 threads per row)
  const int sc   = t & 15;

  float p2r[2];
  p2r[0] = P2[w * 32 + l15];
  p2r[1] = P2[w * 32 + 16 + l15];

  float colmin[2] = {3.4e38f, 3.4e38f};
  float rs = 0.0f;          // row-min sqrt accumulator (valid for t < 64)

  // ---- prologue: prefetch tile 0 into regs ----
  // zA[q]: float4 index 2*sc + (q>>1)*32 + (q&1) of row (row0 + srow)
  float4 zA[4];
  {
    const float4* Zv = (const float4*)Z + (size_t)(blockIdx.x * TILES * BM + srow) * (DDIM / 4);
    #pragma unroll
    for (int q = 0; q < 4; ++q) zA[q] = Zv[2 * sc + (q >> 1) * 32 + (q & 1)];
  }

  for (int tt = 0; tt < TILES; ++tt) {
    // ---- stage A tile (64 x 256) from regs: fp32->bf16 + fp32 z2 ----
    {
      float zacc = 0.f;
      #pragma unroll
      for (int it = 0; it < 2; ++it) {
        float4 a0 = zA[it * 2], a1 = zA[it * 2 + 1];
        zacc += a0.x*a0.x + a0.y*a0.y + a0.z*a0.z + a0.w*a0.w
              + a1.x*a1.x + a1.y*a1.y + a1.z*a1.z + a1.w*a1.w;
        bf16x8 pk;
        pk[0] = (__bf16)a0.x; pk[1] = (__bf16)a0.y; pk[2] = (__bf16)a0.z; pk[3] = (__bf16)a0.w;
        pk[4] = (__bf16)a1.x; pk[5] = (__bf16)a1.y; pk[6] = (__bf16)a1.z; pk[7] = (__bf16)a1.w;
        *(bf16x8*)&A_lds[srow * A_STRIDE + (sc + it * 16) * 8] = pk;
      }
      zacc += __shfl_xor(zacc, 1);
      zacc += __shfl_xor(zacc, 2);
      zacc += __shfl_xor(zacc, 4);
      zacc += __shfl_xor(zacc, 8);
      if (sc == 0) z2s[srow] = zacc;
    }
    __syncthreads();  // B2: A_lds + z2s visible (also orders rowred write-after-read)

    // ---- T14: issue next tile's global loads; fly under the K-loop ----
    if (tt < TILES - 1) {
      const float4* Zv = (const float4*)Z +
          (size_t)((blockIdx.x * TILES + tt + 1) * BM + srow) * (DDIM / 4);
      #pragma unroll
      for (int q = 0; q < 4; ++q) zA[q] = Zv[2 * sc + (q >> 1) * 32 + (q & 1)];
    }

    f32x4 acc[4][2];
    #pragma unroll
    for (int i = 0; i < 4; ++i)
      #pragma unroll
      for (int j = 0; j < 2; ++j)
        acc[i][j] = (f32x4){0.f, 0.f, 0.f, 0.f};

    // ---- K loop: 2 halves of K=128; bg regs live only within a half ----
    #pragma unroll
    for (int kh = 0; kh < 2; ++kh) {
      bf16x8 bg[2][4];
      #pragma unroll
      for (int j = 0; j < 2; ++j)
        #pragma unroll
        for (int ks = 0; ks < 4; ++ks)
          bg[j][ks] = *(const bf16x8*)&PBf[(size_t)((w * 2 + j) * 8 + kh * 4 + ks) * 512 + l * 8];
      #pragma unroll
      for (int ks = 0; ks < 4; ++ks) {
        bf16x8 af[4];
        #pragma unroll
        for (int i = 0; i < 4; ++i)
          af[i] = *(const bf16x8*)&A_lds[(i * 16 + l15) * A_STRIDE + (kh * 4 + ks) * 32 + lg * 8];
        #pragma unroll
        for (int i = 0; i < 4; ++i)
          #pragma unroll
          for (int j = 0; j < 2; ++j)
            acc[i][j] = __builtin_amdgcn_mfma_f32_16x16x32_bf16(af[i], bg[j][ks], acc[i][j], 0, 0, 0);
      }
    }

    // ---- epilogue: sq = z2 + p2 - 2*dot (clamped), row/col mins ----
    float cmin[2] = {3.4e38f, 3.4e38f};
    #pragma unroll
    for (int i = 0; i < 4; ++i) {
      #pragma unroll
      for (int r = 0; r < 4; ++r) {
        int arow = i * 16 + lg * 4 + r;     // C layout: col=lane&15, row=(lane>>4)*4+r
        float z2 = z2s[arow];
        float m = 3.4e38f;
        #pragma unroll
        for (int j = 0; j < 2; ++j) {
          float sq = fmaxf(z2 + p2r[j] - 2.0f * acc[i][j][r], 0.0f);
          m = fminf(m, sq);
          cmin[j] = fminf(cmin[j], sq);
        }
        m = fminf(m, __shfl_xor(m, 1));
        m = fminf(m, __shfl_xor(m, 2));
        m = fminf(m, __shfl_xor(m, 4));
        m = fminf(m, __shfl_xor(m, 8));
        if (l15 == 0) rowred[arow * 16 + w] = m;
      }
    }
    #pragma unroll
    for (int j = 0; j < 2; ++j) {
      float c = cmin[j];
      c = fminf(c, __shfl_xor(c, 16));
      c = fminf(c, __shfl_xor(c, 32));
      colmin[j] = fminf(colmin[j], c);
    }
    __syncthreads();  // B3: rowred visible; also separates A_lds read (K-loop) from next stage
    if (t < 64) {
      float m = rowred[t * 16];
      #pragma unroll
      for (int ww = 1; ww < 16; ++ww) m = fminf(m, rowred[t * 16 + ww]);
      rs += sqrtf(m);
    }
  }

  // ---- block outputs ----
  if (l < 16) {
    colpart[(size_t)blockIdx.x * PROTO + w * 32 + l]      = colmin[0];
    colpart[(size_t)blockIdx.x * PROTO + w * 32 + 16 + l] = colmin[1];
  }
  if (t < 64) {
    float v = rs;
    v += __shfl_xor(v, 1);  v += __shfl_xor(v, 2);  v += __shfl_xor(v, 4);
    v += __shfl_xor(v, 8);  v += __shfl_xor(v, 16); v += __shfl_xor(v, 32);
    if (t == 0) rowpart[blockIdx.x] = v;
  }
}

// ---------------- col reduce: min over 1024 partials per col, then sqrt ----------------
__global__ void col_reduce(const float* __restrict__ colpart, float* __restrict__ colfin) {
  int c = blockIdx.x;    // 512
  int t = threadIdx.x;   // 256
  float m = 3.4e38f;
  for (int g = t; g < GBLK; g += 256) m = fminf(m, colpart[(size_t)g * PROTO + c]);
  #pragma unroll
  for (int mm = 1; mm < 64; mm <<= 1) m = fminf(m, __shfl_xor(m, mm));
  __shared__ float ws4[4];
  if ((t & 63) == 0) ws4[t >> 6] = m;
  __syncthreads();
  if (t == 0) colfin[c] = sqrtf(fminf(fminf(ws4[0], ws4[1]), fminf(ws4[2], ws4[3])));
}

// ---------------- final combine ----------------
__global__ void final_reduce(const float* __restrict__ colfin,
                             const float* __restrict__ rowpart,
                             float* __restrict__ out) {
  int t = threadIdx.x;   // 512
  float sc = colfin[t];
  float sr = rowpart[t] + rowpart[t + 512];
  #pragma unroll
  for (int mm = 1; mm < 64; mm <<= 1) { sc += __shfl_xor(sc, mm); sr += __shfl_xor(sr, mm); }
  __shared__ float wc[8], wr[8];
  if ((t & 63) == 0) { wc[t >> 6] = sc; wr[t >> 6] = sr; }
  __syncthreads();
  if (t == 0) {
    float tc = 0.f, tr = 0.f;
    #pragma unroll
    for (int i = 0; i < 8; ++i) { tc += wc[i]; tr += wr[i]; }
    out[0] = 0.05f * (tr / (float)N_ROWS) + 0.05f * (tc / (float)PROTO);
  }
}

extern "C" void kernel_launch(void* const* d_in, const int* in_sizes, int n_in,
                              void* d_out, int out_size, void* d_ws, size_t ws_size,
                              hipStream_t stream) {
  const float* z  = (const float*)d_in[0];
  const float* pv = (const float*)d_in[1];
  char* ws = (char*)d_ws;
  unsigned short* PBf = (unsigned short*)ws;                              // 262144 B used
  float* P2      = (float*)(ws + 524288);                                 // 2048 B
  float* colpart = (float*)(ws + 524288 + 2048);                          // 2097152 B
  float* rowpart = (float*)(ws + 524288 + 2048 + 2097152);                // 4096 B
  float* colfin  = (float*)(ws + 524288 + 2048 + 2097152 + 4096);         // 2048 B

  prep_proto<<<PROTO, DDIM, 0, stream>>>(pv, PBf, P2);
  proto_main<<<GBLK, 1024, 0, stream>>>(z, PBf, P2, colpart, rowpart);
  col_reduce<<<PROTO, 256, 0, stream>>>(colpart, colfin);
  final_reduce<<<1, 512, 0, stream>>>(colfin, rowpart, (float*)d_out);
}

// Round 4
// 203.900 us; speedup vs baseline: 1.4257x; 1.4257x over previous
//
#include <hip/hip_runtime.h>
#include <hip/hip_bf16.h>

#define N_ROWS 262144
#define DDIM   256
#define PROTO  512
#define BM     64
#define RT     8      // row tiles per block (512 rows/block)
#define RB     512    // row blocks
#define CC     4      // col chunks (128 cols each)
#define NBLK   2048   // RB * CC
#define A_STRIDE 264  // ushorts per row (528B = 33*16B)

typedef __bf16 bf16x8 __attribute__((ext_vector_type(8)));
typedef float  f32x4  __attribute__((ext_vector_type(4)));

// ---------------- prep: prototypes fp32 -> bf16 in MFMA-fragment order, p2 ----------------
// idx = (p>>4)*4096 + (k>>5)*512 + ((((k>>3)&3)*16) + (p&15))*8 + (k&7)
__global__ void prep_proto(const float* __restrict__ Pm,
                           unsigned short* __restrict__ PBf,
                           float* __restrict__ P2) {
  int p = blockIdx.x;     // 512
  int k = threadIdx.x;    // 256
  float v = Pm[p * DDIM + k];
  int idx = (p >> 4) * 4096 + (k >> 5) * 512 + ((((k >> 3) & 3) * 16) + (p & 15)) * 8 + (k & 7);
  ((__bf16*)PBf)[idx] = (__bf16)v;
  float sq = v * v;
  #pragma unroll
  for (int m = 1; m < 64; m <<= 1) sq += __shfl_xor(sq, m);
  __shared__ float ws4[4];
  if ((k & 63) == 0) ws4[k >> 6] = sq;
  __syncthreads();
  if (k == 0) P2[p] = (ws4[0] + ws4[1]) + (ws4[2] + ws4[3]);
}

// ---------------- main: fused GEMM + row/col min ----------------
// 2048 blocks x 256 threads (4 waves, 1 wave/SIMD -> 256-reg budget at 2 blocks/CU).
// Sibling swizzle: cc = (bid>>3)&3, rb = ((bid>>5)<<3)|(bid&7). Siblings (same rb,
// cc=0..3) share bid%8 -> same XCD -> Z rows L2-shared.
// Block: rows [rb*512, rb*512+512) as 8 tiles of 64; cols [cc*128, cc*128+128).
// Wave w owns cols [cc*128+w*32, +32); its full-K B slice lives in 64 VGPRs, loaded once.
__global__ __launch_bounds__(256, 2)
void proto_main(const float* __restrict__ Z, const unsigned short* __restrict__ PBf,
                const float* __restrict__ P2, float* __restrict__ colpart,
                float* __restrict__ rowminpart) {
  __shared__ __align__(16) unsigned short A_lds[BM * A_STRIDE];  // 33792 B
  __shared__ float z2s[BM];
  __shared__ float rowred[BM * 4];

  const int t   = threadIdx.x;
  const int w   = t >> 6;   // wave 0..3
  const int l   = t & 63;
  const int l15 = l & 15;
  const int lg  = l >> 4;   // 0..3

  const int bid = blockIdx.x;
  const int cc  = (bid >> 3) & 3;
  const int rb  = ((bid >> 5) << 3) | (bid & 7);

  // ---- B slice into registers: 2 col-frags x 8 k-steps, 64 VGPR, loaded once ----
  bf16x8 bg[2][8];
  #pragma unroll
  for (int j = 0; j < 2; ++j)
    #pragma unroll
    for (int ks = 0; ks < 8; ++ks)
      bg[j][ks] = *(const bf16x8*)&PBf[(size_t)(((cc * 8 + w * 2 + j) * 8) + ks) * 512 + l * 8];

  float p2r[2];
  p2r[0] = P2[cc * 128 + w * 32 + l15];
  p2r[1] = P2[cc * 128 + w * 32 + 16 + l15];

  float colmin[2] = {3.4e38f, 3.4e38f};

  const int srow = t >> 2;  // staging row 0..63 (4 threads/row)
  const int sc4  = t & 3;
  const size_t rowbase = (size_t)rb * (RT * BM);

  for (int tt = 0; tt < RT; ++tt) {
    // ---- stage A tile (64 x 256): batched 16x float4 loads -> bf16 LDS + fp32 z2 ----
    {
      const float4* Zv = (const float4*)Z + (rowbase + tt * BM + srow) * (DDIM / 4);
      float4 za[16];
      #pragma unroll
      for (int m = 0; m < 8; ++m) {
        za[2 * m]     = Zv[(sc4 + m * 4) * 2];
        za[2 * m + 1] = Zv[(sc4 + m * 4) * 2 + 1];
      }
      float zacc = 0.f;
      #pragma unroll
      for (int m = 0; m < 8; ++m) {
        float4 a0 = za[2 * m], a1 = za[2 * m + 1];
        zacc += a0.x*a0.x + a0.y*a0.y + a0.z*a0.z + a0.w*a0.w
              + a1.x*a1.x + a1.y*a1.y + a1.z*a1.z + a1.w*a1.w;
        bf16x8 pk;
        pk[0] = (__bf16)a0.x; pk[1] = (__bf16)a0.y; pk[2] = (__bf16)a0.z; pk[3] = (__bf16)a0.w;
        pk[4] = (__bf16)a1.x; pk[5] = (__bf16)a1.y; pk[6] = (__bf16)a1.z; pk[7] = (__bf16)a1.w;
        *(bf16x8*)&A_lds[srow * A_STRIDE + (sc4 + m * 4) * 8] = pk;
      }
      zacc += __shfl_xor(zacc, 1);
      zacc += __shfl_xor(zacc, 2);
      if (sc4 == 0) z2s[srow] = zacc;
    }
    __syncthreads();  // B2: A_lds + z2s visible (also orders rowred read -> next write)

    f32x4 acc[4][2];
    #pragma unroll
    for (int i = 0; i < 4; ++i)
      #pragma unroll
      for (int j = 0; j < 2; ++j)
        acc[i][j] = (f32x4){0.f, 0.f, 0.f, 0.f};

    // ---- K loop: 8 steps of BK=32; B from regs, zero barriers ----
    #pragma unroll
    for (int ks = 0; ks < 8; ++ks) {
      bf16x8 af[4];
      #pragma unroll
      for (int i = 0; i < 4; ++i)
        af[i] = *(const bf16x8*)&A_lds[(i * 16 + l15) * A_STRIDE + ks * 32 + lg * 8];
      #pragma unroll
      for (int i = 0; i < 4; ++i)
        #pragma unroll
        for (int j = 0; j < 2; ++j)
          acc[i][j] = __builtin_amdgcn_mfma_f32_16x16x32_bf16(af[i], bg[j][ks], acc[i][j], 0, 0, 0);
    }

    // ---- epilogue: sq = z2 + p2 - 2*dot (clamped), row/col mins ----
    float cmin[2] = {3.4e38f, 3.4e38f};
    #pragma unroll
    for (int i = 0; i < 4; ++i) {
      #pragma unroll
      for (int r = 0; r < 4; ++r) {
        int arow = i * 16 + lg * 4 + r;     // C layout: col=lane&15, row=(lane>>4)*4+r
        float z2 = z2s[arow];
        float m = 3.4e38f;
        #pragma unroll
        for (int j = 0; j < 2; ++j) {
          float sq = fmaxf(z2 + p2r[j] - 2.0f * acc[i][j][r], 0.0f);
          m = fminf(m, sq);
          cmin[j] = fminf(cmin[j], sq);
        }
        m = fminf(m, __shfl_xor(m, 1));
        m = fminf(m, __shfl_xor(m, 2));
        m = fminf(m, __shfl_xor(m, 4));
        m = fminf(m, __shfl_xor(m, 8));
        if (l15 == 0) rowred[arow * 4 + w] = m;
      }
    }
    #pragma unroll
    for (int j = 0; j < 2; ++j) {
      float c = cmin[j];
      c = fminf(c, __shfl_xor(c, 16));
      c = fminf(c, __shfl_xor(c, 32));
      colmin[j] = fminf(colmin[j], c);
    }
    __syncthreads();  // B3: rowred visible; separates A_lds reads from next stage
    if (t < 64) {
      float m = fminf(fminf(rowred[t * 4], rowred[t * 4 + 1]),
                      fminf(rowred[t * 4 + 2], rowred[t * 4 + 3]));
      rowminpart[(size_t)cc * N_ROWS + rowbase + tt * BM + t] = m;  // coalesced 64 floats
    }
  }

  // ---- block col-min outputs ----
  if (l < 16) {
    colpart[(size_t)rb * PROTO + cc * 128 + w * 32 + l]      = colmin[0];
    colpart[(size_t)rb * PROTO + cc * 128 + w * 32 + 16 + l] = colmin[1];
  }
}

// ---------------- col reduce: min over 512 row-block partials per col, sqrt ----------------
__global__ void col_reduce(const float* __restrict__ colpart, float* __restrict__ colfin) {
  int c = blockIdx.x;    // 512
  int t = threadIdx.x;   // 256
  float m = 3.4e38f;
  for (int g = t; g < RB; g += 256) m = fminf(m, colpart[(size_t)g * PROTO + c]);
  #pragma unroll
  for (int mm = 1; mm < 64; mm <<= 1) m = fminf(m, __shfl_xor(m, mm));
  __shared__ float ws4[4];
  if ((t & 63) == 0) ws4[t >> 6] = m;
  __syncthreads();
  if (t == 0) colfin[c] = sqrtf(fminf(fminf(ws4[0], ws4[1]), fminf(ws4[2], ws4[3])));
}

// ---------------- row reduce: min over 4 col-chunk partials, sqrt, block sum ----------------
__global__ void row_reduce(const float* __restrict__ rowminpart, float* __restrict__ rowsum) {
  int t = threadIdx.x;                       // 256
  size_t grow = (size_t)blockIdx.x * 256 + t;  // 1024 blocks
  float m = fminf(fminf(rowminpart[grow],              rowminpart[N_ROWS + grow]),
                  fminf(rowminpart[2 * N_ROWS + grow], rowminpart[3 * N_ROWS + grow]));
  float s = sqrtf(m);
  #pragma unroll
  for (int mm = 1; mm < 64; mm <<= 1) s += __shfl_xor(s, mm);
  __shared__ float ws4[4];
  if ((t & 63) == 0) ws4[t >> 6] = s;
  __syncthreads();
  if (t == 0) rowsum[blockIdx.x] = (ws4[0] + ws4[1]) + (ws4[2] + ws4[3]);
}

// ---------------- final combine ----------------
__global__ void final_reduce(const float* __restrict__ colfin,
                             const float* __restrict__ rowsum,
                             float* __restrict__ out) {
  int t = threadIdx.x;   // 512
  float sc = colfin[t];
  float sr = rowsum[t] + rowsum[t + 512];
  #pragma unroll
  for (int mm = 1; mm < 64; mm <<= 1) { sc += __shfl_xor(sc, mm); sr += __shfl_xor(sr, mm); }
  __shared__ float wc[8], wr[8];
  if ((t & 63) == 0) { wc[t >> 6] = sc; wr[t >> 6] = sr; }
  __syncthreads();
  if (t == 0) {
    float tc = 0.f, tr = 0.f;
    #pragma unroll
    for (int i = 0; i < 8; ++i) { tc += wc[i]; tr += wr[i]; }
    out[0] = 0.05f * (tr / (float)N_ROWS) + 0.05f * (tc / (float)PROTO);
  }
}

extern "C" void kernel_launch(void* const* d_in, const int* in_sizes, int n_in,
                              void* d_out, int out_size, void* d_ws, size_t ws_size,
                              hipStream_t stream) {
  const float* z  = (const float*)d_in[0];
  const float* pv = (const float*)d_in[1];
  char* ws = (char*)d_ws;
  size_t off = 0;
  unsigned short* PBf = (unsigned short*)(ws + off); off += 262144;        // 256 KB
  float* P2         = (float*)(ws + off); off += 2048;
  float* colpart    = (float*)(ws + off); off += (size_t)RB * PROTO * 4;   // 1 MB
  float* rowminpart = (float*)(ws + off); off += (size_t)CC * N_ROWS * 4;  // 4 MB
  float* rowsum     = (float*)(ws + off); off += 4096;
  float* colfin     = (float*)(ws + off); off += 2048;

  prep_proto<<<PROTO, DDIM, 0, stream>>>(pv, PBf, P2);
  proto_main<<<NBLK, 256, 0, stream>>>(z, PBf, P2, colpart, rowminpart);
  col_reduce<<<PROTO, 256, 0, stream>>>(colpart, colfin);
  row_reduce<<<N_ROWS / 256, 256, 0, stream>>>(rowminpart, rowsum);
  final_reduce<<<1, 512, 0, stream>>>(colfin, rowsum, (float*)d_out);
}

// Round 5
// 147.743 us; speedup vs baseline: 1.9676x; 1.3801x over previous
//
#include <hip/hip_runtime.h>
#include <hip/hip_bf16.h>

#define N_ROWS 262144
#define DDIM   256
#define PROTO  512
#define BM     64
#define RTG    4096   // row tiles (groups)
#define NBLK   8192   // RTG * 2 col-chunks
#define A_STRIDE 264  // ushorts per row (528B = 33*16B): K-loop reads are 2-way (free)

typedef __bf16 bf16x8 __attribute__((ext_vector_type(8)));
typedef float  f32x4  __attribute__((ext_vector_type(4)));

// ---------------- prep: prototypes fp32 -> bf16 in MFMA-fragment order, p2 ----------------
// idx = (p>>4)*4096 + (k>>5)*512 + ((((k>>3)&3)*16) + (p&15))*8 + (k&7)
__global__ void prep_proto(const float* __restrict__ Pm,
                           unsigned short* __restrict__ PBf,
                           float* __restrict__ P2) {
  int p = blockIdx.x;     // 512
  int k = threadIdx.x;    // 256
  float v = Pm[p * DDIM + k];
  int idx = (p >> 4) * 4096 + (k >> 5) * 512 + ((((k >> 3) & 3) * 16) + (p & 15)) * 8 + (k & 7);
  ((__bf16*)PBf)[idx] = (__bf16)v;
  float sq = v * v;
  #pragma unroll
  for (int m = 1; m < 64; m <<= 1) sq += __shfl_xor(sq, m);
  __shared__ float ws4[4];
  if ((k & 63) == 0) ws4[k >> 6] = sq;
  __syncthreads();
  if (k == 0) P2[p] = (ws4[0] + ws4[1]) + (ws4[2] + ws4[3]);
}

__global__ void init_colbits(unsigned int* __restrict__ cb) {
  cb[threadIdx.x] = 0x7f7f7f7fu;   // 3.39e38 > any possible sq
}

// ---------------- main: fused GEMM + row/col min, ONE 64-row tile per block ----------------
// 8192 blocks x 256 threads (4 waves; __launch_bounds__(256,2) -> 256-reg budget, 2 blocks/CU).
// bid decode keeps bid%8 for siblings: g = ((bid>>4)<<3)|(bid&7) in 0..4095, cc = (bid>>3)&1.
// Siblings (same g, cc=0/1) share an XCD -> Z tile fetched once from HBM, once from L2.
// Wave w owns 64 proto cols [cc*256 + w*64, +64); full-K B slice in 128 VGPRs, loaded once.
__global__ __launch_bounds__(256, 2)
void proto_main(const float* __restrict__ Z, const unsigned short* __restrict__ PBf,
                const float* __restrict__ P2, unsigned int* __restrict__ colbits,
                float* __restrict__ rowminpart) {
  __shared__ __align__(16) unsigned short A_lds[BM * A_STRIDE];  // 33792 B
  __shared__ float z2s[BM];
  __shared__ float rowred[BM * 4];

  const int t   = threadIdx.x;
  const int w   = t >> 6;   // wave 0..3
  const int l   = t & 63;
  const int l15 = l & 15;
  const int lg  = l >> 4;   // 0..3

  const int bid = blockIdx.x;
  const int g   = ((bid >> 4) << 3) | (bid & 7);  // row tile 0..4095
  const int cc  = (bid >> 3) & 1;                 // col chunk 0..1
  const size_t row0 = (size_t)g * BM;

  // ---- stage A tile (64 x 256): 16 batched float4 loads -> bf16 LDS + fp32 z2 ----
  const int srow = t >> 2;  // 4 threads per row
  const int sc4  = t & 3;
  {
    const float4* Zv = (const float4*)Z + (row0 + srow) * (DDIM / 4);
    float4 za[16];
    #pragma unroll
    for (int m = 0; m < 8; ++m) {
      za[2 * m]     = Zv[(sc4 + m * 4) * 2];
      za[2 * m + 1] = Zv[(sc4 + m * 4) * 2 + 1];
    }
    float zacc = 0.f;
    #pragma unroll
    for (int m = 0; m < 8; ++m) {
      float4 a0 = za[2 * m], a1 = za[2 * m + 1];
      zacc += a0.x*a0.x + a0.y*a0.y + a0.z*a0.z + a0.w*a0.w
            + a1.x*a1.x + a1.y*a1.y + a1.z*a1.z + a1.w*a1.w;
      bf16x8 pk;
      pk[0] = (__bf16)a0.x; pk[1] = (__bf16)a0.y; pk[2] = (__bf16)a0.z; pk[3] = (__bf16)a0.w;
      pk[4] = (__bf16)a1.x; pk[5] = (__bf16)a1.y; pk[6] = (__bf16)a1.z; pk[7] = (__bf16)a1.w;
      *(bf16x8*)&A_lds[srow * A_STRIDE + (sc4 + m * 4) * 8] = pk;
    }
    zacc += __shfl_xor(zacc, 1);
    zacc += __shfl_xor(zacc, 2);
    if (sc4 == 0) z2s[srow] = zacc;
  }

  // ---- B slice into registers: 4 col-frags x 8 k-steps = 128 VGPR, loaded once (L2-hot) ----
  bf16x8 bg[4][8];
  #pragma unroll
  for (int j = 0; j < 4; ++j)
    #pragma unroll
    for (int ks = 0; ks < 8; ++ks)
      bg[j][ks] = *(const bf16x8*)&PBf[(size_t)(((cc * 16 + w * 4 + j) * 8) + ks) * 512 + l * 8];

  float p2r[4];
  #pragma unroll
  for (int j = 0; j < 4; ++j) p2r[j] = P2[cc * 256 + w * 64 + j * 16 + l15];

  __syncthreads();  // A_lds + z2s visible

  f32x4 acc[4][4];
  #pragma unroll
  for (int i = 0; i < 4; ++i)
    #pragma unroll
    for (int j = 0; j < 4; ++j)
      acc[i][j] = (f32x4){0.f, 0.f, 0.f, 0.f};

  // ---- K loop: 8 steps of BK=32; B from regs, zero barriers, MFMA:ds = 4:1 ----
  #pragma unroll
  for (int ks = 0; ks < 8; ++ks) {
    bf16x8 af[4];
    #pragma unroll
    for (int i = 0; i < 4; ++i)
      af[i] = *(const bf16x8*)&A_lds[(i * 16 + l15) * A_STRIDE + ks * 32 + lg * 8];
    #pragma unroll
    for (int i = 0; i < 4; ++i)
      #pragma unroll
      for (int j = 0; j < 4; ++j)
        acc[i][j] = __builtin_amdgcn_mfma_f32_16x16x32_bf16(af[i], bg[j][ks], acc[i][j], 0, 0, 0);
  }

  // ---- epilogue: sq = z2 + p2 - 2*dot (clamped), row/col mins ----
  float cmin[4] = {3.4e38f, 3.4e38f, 3.4e38f, 3.4e38f};
  #pragma unroll
  for (int i = 0; i < 4; ++i) {
    #pragma unroll
    for (int r = 0; r < 4; ++r) {
      int arow = i * 16 + lg * 4 + r;     // C layout: col=lane&15, row=(lane>>4)*4+r
      float z2 = z2s[arow];
      float m = 3.4e38f;
      #pragma unroll
      for (int j = 0; j < 4; ++j) {
        float sq = fmaxf(z2 + p2r[j] - 2.0f * acc[i][j][r], 0.0f);
        m = fminf(m, sq);
        cmin[j] = fminf(cmin[j], sq);
      }
      m = fminf(m, __shfl_xor(m, 1));
      m = fminf(m, __shfl_xor(m, 2));
      m = fminf(m, __shfl_xor(m, 4));
      m = fminf(m, __shfl_xor(m, 8));
      if (l15 == 0) rowred[arow * 4 + w] = m;
    }
  }
  // col-min across row-groups, then one deterministic atomicMin per col (uint-bit trick)
  #pragma unroll
  for (int j = 0; j < 4; ++j) {
    float c = cmin[j];
    c = fminf(c, __shfl_xor(c, 16));
    c = fminf(c, __shfl_xor(c, 32));
    cmin[j] = c;
  }
  if (l < 16) {
    #pragma unroll
    for (int j = 0; j < 4; ++j)
      atomicMin(&colbits[cc * 256 + w * 64 + j * 16 + l], __float_as_uint(cmin[j]));
  }
  __syncthreads();  // rowred visible
  if (t < 64) {
    float m = fminf(fminf(rowred[t * 4], rowred[t * 4 + 1]),
                    fminf(rowred[t * 4 + 2], rowred[t * 4 + 3]));
    rowminpart[(size_t)cc * N_ROWS + row0 + t] = m;  // coalesced 64 floats
  }
}

// ---------------- row reduce: min over 2 col-chunk partials, sqrt, block sum ----------------
__global__ void row_reduce(const float* __restrict__ rowminpart, float* __restrict__ rowsum) {
  int t = threadIdx.x;                         // 256
  size_t grow = (size_t)blockIdx.x * 256 + t;  // 1024 blocks
  float m = fminf(rowminpart[grow], rowminpart[N_ROWS + grow]);
  float s = sqrtf(m);
  #pragma unroll
  for (int mm = 1; mm < 64; mm <<= 1) s += __shfl_xor(s, mm);
  __shared__ float ws4[4];
  if ((t & 63) == 0) ws4[t >> 6] = s;
  __syncthreads();
  if (t == 0) rowsum[blockIdx.x] = (ws4[0] + ws4[1]) + (ws4[2] + ws4[3]);
}

// ---------------- final combine ----------------
__global__ void final_reduce(const unsigned int* __restrict__ colbits,
                             const float* __restrict__ rowsum,
                             float* __restrict__ out) {
  int t = threadIdx.x;   // 512
  float sc = sqrtf(__uint_as_float(colbits[t]));
  float sr = rowsum[t] + rowsum[t + 512];
  #pragma unroll
  for (int mm = 1; mm < 64; mm <<= 1) { sc += __shfl_xor(sc, mm); sr += __shfl_xor(sr, mm); }
  __shared__ float wc[8], wr[8];
  if ((t & 63) == 0) { wc[t >> 6] = sc; wr[t >> 6] = sr; }
  __syncthreads();
  if (t == 0) {
    float tc = 0.f, tr = 0.f;
    #pragma unroll
    for (int i = 0; i < 8; ++i) { tc += wc[i]; tr += wr[i]; }
    out[0] = 0.05f * (tr / (float)N_ROWS) + 0.05f * (tc / (float)PROTO);
  }
}

extern "C" void kernel_launch(void* const* d_in, const int* in_sizes, int n_in,
                              void* d_out, int out_size, void* d_ws, size_t ws_size,
                              hipStream_t stream) {
  const float* z  = (const float*)d_in[0];
  const float* pv = (const float*)d_in[1];
  char* ws = (char*)d_ws;
  size_t off = 0;
  unsigned short* PBf  = (unsigned short*)(ws + off); off += 262144;        // 256 KB
  float* P2            = (float*)(ws + off);          off += 2048;
  unsigned int* colbits= (unsigned int*)(ws + off);   off += 2048;
  float* rowminpart    = (float*)(ws + off);          off += (size_t)2 * N_ROWS * 4;  // 2 MB
  float* rowsum        = (float*)(ws + off);          off += 4096;

  prep_proto<<<PROTO, DDIM, 0, stream>>>(pv, PBf, P2);
  init_colbits<<<1, PROTO, 0, stream>>>(colbits);
  proto_main<<<NBLK, 256, 0, stream>>>(z, PBf, P2, colbits, rowminpart);
  row_reduce<<<N_ROWS / 256, 256, 0, stream>>>(rowminpart, rowsum);
  final_reduce<<<1, PROTO, 0, stream>>>(colbits, rowsum, (float*)d_out);
}